// Round 5
// baseline (2296.698 us; speedup 1.0000x reference)
//
#include <hip/hip_runtime.h>

#define B_  64
#define H_  32
#define D_  4096
#define KD  128
#define VD  128
#define M_  4095
#define M1_ 4096
#define NCHUNK 32
#define LOG2E 1.44269504088896f

// ---- workspace layout (float offsets) ----
#define WS_P      0ull
#define WS_Q      4456448ull
#define WS_STATS  4718592ull
#define WS_O      4849664ull
#define WS_OPART  5111808ull

// ---------------- K1a: partial projections (q, k_new, v_new) ----------------
// grid (16 d-chunks, 34 hx) ; hx<32 -> Wq[h], hx==32 -> Wk, hx==33 -> Wv
__global__ __launch_bounds__(256) void k_proj_partial(
    const float* __restrict__ x, const float* __restrict__ Wq,
    const float* __restrict__ Wk, const float* __restrict__ Wv,
    float* __restrict__ P) {
  __shared__ float xs[64][256];   // 64 KB -> 2 blocks/CU
  const int dc = blockIdx.x;      // 0..15
  const int hx = blockIdx.y;      // 0..33
  const int t  = threadIdx.x;
  const float* xsrc = x + dc * 256;
  #pragma unroll
  for (int j = 0; j < 16; ++j) {
    int f = t + 256 * j;          // f4 index 0..4095
    int row = f >> 6, c4 = f & 63;
    *(float4*)&xs[row][c4 * 4] =
        *(const float4*)(xsrc + (size_t)row * D_ + c4 * 4);
  }
  __syncthreads();
  const int bq = t >> 4;          // 0..15 (4 b each)
  const int kg = t & 15;          // 0..15 (8 k each)
  const int b0 = bq * 4;
  const float* W = (hx < H_) ? (Wq + (size_t)hx * D_ * KD)
                             : ((hx == H_) ? Wk : Wv);
  const float* wp = W + (size_t)(dc * 256) * KD + kg * 8;
  float acc[4][8];
  #pragma unroll
  for (int i = 0; i < 4; ++i)
    #pragma unroll
    for (int j = 0; j < 8; ++j) acc[i][j] = 0.f;
  #pragma unroll 8
  for (int d = 0; d < 256; ++d) {   // unroll 8: keep ~16 W loads in flight
    float4 w0 = *(const float4*)(wp + (size_t)d * KD);
    float4 w1 = *(const float4*)(wp + (size_t)d * KD + 4);
    float xv[4];
    #pragma unroll
    for (int i = 0; i < 4; ++i) xv[i] = xs[b0 + i][d];
    #pragma unroll
    for (int i = 0; i < 4; ++i) {
      acc[i][0] += xv[i] * w0.x; acc[i][1] += xv[i] * w0.y;
      acc[i][2] += xv[i] * w0.z; acc[i][3] += xv[i] * w0.w;
      acc[i][4] += xv[i] * w1.x; acc[i][5] += xv[i] * w1.y;
      acc[i][6] += xv[i] * w1.z; acc[i][7] += xv[i] * w1.w;
    }
  }
  #pragma unroll
  for (int i = 0; i < 4; ++i) {
    size_t base = ((size_t)(dc * 64 + b0 + i) * 34 + hx) * KD + kg * 8;
    *(float4*)&P[base]     = make_float4(acc[i][0], acc[i][1], acc[i][2], acc[i][3]);
    *(float4*)&P[base + 4] = make_float4(acc[i][4], acc[i][5], acc[i][6], acc[i][7]);
  }
}

// ---------------- K1b: reduce partials -> q, Kc[.,M,:], Vc[.,M,:] ----------
__global__ __launch_bounds__(256) void k_proj_reduce(
    const float* __restrict__ P, float* __restrict__ q,
    float* __restrict__ Kc, float* __restrict__ Vc) {
  int i = blockIdx.x * 256 + threadIdx.x;  // < 64*34*128 = 278528
  int k = i & 127;
  int hx = (i >> 7) % 34;
  int b = i / (128 * 34);
  float s = 0.f;
  #pragma unroll
  for (int dc = 0; dc < 16; ++dc)
    s += P[(size_t)dc * (64 * 34 * 128) + (size_t)(b * 34 + hx) * 128 + k];
  if (hx < H_)       q[((size_t)b * H_ + hx) * KD + k] = s;
  else if (hx == H_) Kc[((size_t)b * M1_ + M_) * KD + k] = s;
  else               Vc[((size_t)b * M1_ + M_) * VD + k] = s;
}

// ---------------- K2: flash attention chunk kernel (global-direct K/V) -----
// grid (32 m-chunks of 128, 64 b).
// Logits: thread-per-m-row; K row held in registers (reused for 16 h),
//         q via LDS broadcasts. Kc copy from the same registers.
// PV:     thread-per-(v4,h4); V rows read coalesced from global (L1/L2 reuse
//         across h-groups). Vc copy from the same registers.
// LDS: wl_t (h-major logits) + union{qs, wl_m (m-major weights)} = 34.5 KB
// -> 4 blocks/CU; only 4 barriers per block.
__global__ __launch_bounds__(256, 4) void k_flash(
    const float* __restrict__ prevK, const float* __restrict__ prevV,
    const float* __restrict__ q, float* __restrict__ Kc, float* __restrict__ Vc,
    float* __restrict__ o_part, float* __restrict__ stats) {
  __shared__ float wl_t[32][132];          // logits, h-major (16.9 KB)
  __shared__ float upool[128 * 36];        // union: qs[32][128] / wl_m[128][36]
  float (*qs)[128]  = (float(*)[128])upool;
  float (*wl_m)[36] = (float(*)[36])upool;

  const int chunk = blockIdx.x;    // 0..31
  const int b = blockIdx.y;
  const int t = threadIdx.x;
  const int m0 = chunk * 128;

  // ---- stage q tile [32][128] into LDS ----
  const float* qsrc = q + (size_t)b * H_ * KD;
  #pragma unroll
  for (int j = 0; j < 4; ++j) {
    int f = t + 256 * j, row = f >> 5, c4 = f & 31;
    *(float4*)&qs[row][c4 * 4] =
        *(const float4*)(qsrc + (size_t)row * KD + c4 * 4);
  }
  __syncthreads();

  // ---- Phase 1: logits. thread: m row = t&127, h half = t>>7 ----
  {
    const int ml = t & 127, hh = t >> 7;
    const int m = m0 + ml;
    const int h0 = hh * 16;
    const float* krow = (m < M_) ? (prevK + ((size_t)b * M_ + m) * KD)
                                 : (Kc + ((size_t)b * M1_ + M_) * KD);
    float* kcrow = Kc + ((size_t)b * M1_ + m) * KD;
    const bool do_store = (hh == 0) && (m < M_);
    float acc[16];
    #pragma unroll
    for (int i = 0; i < 16; ++i) acc[i] = 0.f;
    #pragma unroll
    for (int lb = 0; lb < 4; ++lb) {       // 4 line-blocks of 32 floats (128B)
      float4 kv[8];
      #pragma unroll
      for (int j = 0; j < 8; ++j) kv[j] = *(const float4*)(krow + lb * 32 + j * 4);
      if (do_store) {
        #pragma unroll
        for (int j = 0; j < 8; ++j) *(float4*)(kcrow + lb * 32 + j * 4) = kv[j];
      }
      #pragma unroll
      for (int hi = 0; hi < 16; ++hi) {
        float s = 0.f;
        #pragma unroll
        for (int j = 0; j < 8; ++j) {
          float4 qv = *(const float4*)&qs[h0 + hi][lb * 32 + j * 4];  // broadcast
          s += kv[j].x * qv.x + kv[j].y * qv.y + kv[j].z * qv.z + kv[j].w * qv.w;
        }
        acc[hi] += s;
      }
    }
    #pragma unroll
    for (int hi = 0; hi < 16; ++hi) wl_t[h0 + hi][ml] = acc[hi];
  }
  __syncthreads();   // wl_t complete; qs dead -> upool becomes wl_m

  // ---- Phase 2: chunk-local softmax; write weights m-major into wl_m ----
  {
    const int h = t >> 3, s8 = t & 7;      // 8 threads per h
    float vals[16];
    float mx = -3.402823466e38f;
    #pragma unroll
    for (int i = 0; i < 16; ++i) {
      vals[i] = wl_t[h][i * 8 + s8];
      mx = fmaxf(mx, vals[i]);
    }
    mx = fmaxf(mx, __shfl_xor(mx, 1));
    mx = fmaxf(mx, __shfl_xor(mx, 2));
    mx = fmaxf(mx, __shfl_xor(mx, 4));
    float sum = 0.f;
    #pragma unroll
    for (int i = 0; i < 16; ++i) {
      float e = exp2f((vals[i] - mx) * LOG2E);
      wl_m[i * 8 + s8][h] = e;
      sum += e;
    }
    sum += __shfl_xor(sum, 1);
    sum += __shfl_xor(sum, 2);
    sum += __shfl_xor(sum, 4);
    if (s8 == 0) {
      size_t sb = (((size_t)b * H_ + h) * NCHUNK + chunk) * 2;
      stats[sb]     = mx;
      stats[sb + 1] = sum;
    }
  }
  __syncthreads();   // wl_m ready

  // ---- Phase 3: PV. thread: v4 = t&31, h-quad = t>>5 ----
  {
    const int v4 = t & 31, hoct = t >> 5;
    const int h0v = hoct * 4;
    float4 a0 = {0,0,0,0}, a1 = {0,0,0,0}, a2 = {0,0,0,0}, a3 = {0,0,0,0};
    #pragma unroll 4
    for (int mm = 0; mm < 128; ++mm) {
      int mv = m0 + mm;
      const float* vrow = (mv < M_) ? (prevV + ((size_t)b * M_ + mv) * VD)
                                    : (Vc + ((size_t)b * M1_ + M_) * VD);
      float4 gv = *(const float4*)(vrow + v4 * 4);          // coalesced
      if (hoct == 0 && mv < M_)
        *(float4*)(Vc + ((size_t)b * M1_ + mv) * VD + v4 * 4) = gv;
      float4 w4 = *(const float4*)&wl_m[mm][h0v];           // broadcast
      a0.x += w4.x * gv.x; a0.y += w4.x * gv.y; a0.z += w4.x * gv.z; a0.w += w4.x * gv.w;
      a1.x += w4.y * gv.x; a1.y += w4.y * gv.y; a1.z += w4.y * gv.z; a1.w += w4.y * gv.w;
      a2.x += w4.z * gv.x; a2.y += w4.z * gv.y; a2.z += w4.z * gv.z; a2.w += w4.z * gv.w;
      a3.x += w4.w * gv.x; a3.y += w4.w * gv.y; a3.z += w4.w * gv.z; a3.w += w4.w * gv.w;
    }
    size_t base = ((size_t)(chunk * B_ + b) * H_ + h0v) * VD + v4 * 4;
    *(float4*)&o_part[base]            = a0;
    *(float4*)&o_part[base + VD]       = a1;
    *(float4*)&o_part[base + 2 * VD]   = a2;
    *(float4*)&o_part[base + 3 * VD]   = a3;
  }
}

// ---------------- K3: flash combine -> o -----------------------------------
// grid 2048 = (b*H + h); 128 threads (one per v)
__global__ __launch_bounds__(128) void k_combine(
    const float* __restrict__ o_part, const float* __restrict__ stats,
    float* __restrict__ o) {
  const int bh = blockIdx.x;
  const int t = threadIdx.x;
  __shared__ float st[64];
  if (t < 64) st[t] = stats[(size_t)bh * 64 + t];
  __syncthreads();
  float M = -3.402823466e38f;
  #pragma unroll
  for (int c = 0; c < NCHUNK; ++c) M = fmaxf(M, st[2 * c]);
  float wc[NCHUNK];
  float denom = 0.f;
  #pragma unroll
  for (int c = 0; c < NCHUNK; ++c) {
    float e = exp2f((st[2 * c] - M) * LOG2E);
    wc[c] = e;
    denom += st[2 * c + 1] * e;
  }
  const float inv = 1.0f / denom;
  const int b = bh >> 5, h = bh & 31;
  float acc = 0.f;
  #pragma unroll 4
  for (int c = 0; c < NCHUNK; ++c)
    acc += wc[c] * o_part[((size_t)(c * B_ + b) * H_ + h) * VD + t];
  o[(size_t)bh * VD + t] = acc * inv;
}

// ---------------- K5: partial y = o . Wo -----------------------------------
// grid (32 d-chunks of 128, 16 hv-chunks of 256)
__global__ __launch_bounds__(256) void k_out_partial(
    const float* __restrict__ o, const float* __restrict__ Wo,
    float* __restrict__ Py) {
  __shared__ float os[64][256];   // 64 KB -> 2 blocks/CU
  const int dc = blockIdx.x;      // 0..31
  const int hvc = blockIdx.y;     // 0..15
  const int t = threadIdx.x;
  #pragma unroll
  for (int j = 0; j < 16; ++j) {
    int f = t + 256 * j;          // 0..4095 f4 over [64][64]
    int row = f >> 6, c4 = f & 63;
    *(float4*)&os[row][c4 * 4] =
        *(const float4*)(o + (size_t)row * 4096 + hvc * 256 + c4 * 4);
  }
  __syncthreads();
  const int bq = t >> 4, dg = t & 15;
  const int b0 = bq * 4;
  const float* wp = Wo + (size_t)(hvc * 256) * D_ + dc * 128 + dg * 8;
  float acc[4][8];
  #pragma unroll
  for (int i = 0; i < 4; ++i)
    #pragma unroll
    for (int j = 0; j < 8; ++j) acc[i][j] = 0.f;
  #pragma unroll 8
  for (int hv = 0; hv < 256; ++hv) {  // unroll 8: keep ~16 Wo loads in flight
    float4 w0 = *(const float4*)(wp + (size_t)hv * D_);
    float4 w1 = *(const float4*)(wp + (size_t)hv * D_ + 4);
    float ov[4];
    #pragma unroll
    for (int i = 0; i < 4; ++i) ov[i] = os[b0 + i][hv];
    #pragma unroll
    for (int i = 0; i < 4; ++i) {
      acc[i][0] += ov[i] * w0.x; acc[i][1] += ov[i] * w0.y;
      acc[i][2] += ov[i] * w0.z; acc[i][3] += ov[i] * w0.w;
      acc[i][4] += ov[i] * w1.x; acc[i][5] += ov[i] * w1.y;
      acc[i][6] += ov[i] * w1.z; acc[i][7] += ov[i] * w1.w;
    }
  }
  #pragma unroll
  for (int i = 0; i < 4; ++i) {
    size_t base = ((size_t)hvc * 64 + b0 + i) * 4096 + dc * 128 + dg * 8;
    *(float4*)&Py[base]     = make_float4(acc[i][0], acc[i][1], acc[i][2], acc[i][3]);
    *(float4*)&Py[base + 4] = make_float4(acc[i][4], acc[i][5], acc[i][6], acc[i][7]);
  }
}

// ---------------- K5b: reduce partial y ------------------------------------
__global__ __launch_bounds__(256) void k_yreduce(
    const float* __restrict__ Py, float* __restrict__ y) {
  int i = blockIdx.x * 256 + threadIdx.x;  // < 262144
  float s = 0.f;
  #pragma unroll
  for (int c = 0; c < 16; ++c) s += Py[(size_t)c * 262144 + i];
  y[i] = s;
}

extern "C" void kernel_launch(void* const* d_in, const int* in_sizes, int n_in,
                              void* d_out, int out_size, void* d_ws, size_t ws_size,
                              hipStream_t stream) {
  const float* x     = (const float*)d_in[0];
  const float* prevK = (const float*)d_in[1];
  const float* prevV = (const float*)d_in[2];
  const float* Wq    = (const float*)d_in[3];
  const float* Wk    = (const float*)d_in[4];
  const float* Wv    = (const float*)d_in[5];
  const float* Wo    = (const float*)d_in[6];

  float* y  = (float*)d_out;                 // [64][4096]
  float* Kc = y + (size_t)B_ * D_;           // [64][4096][128]
  float* Vc = Kc + (size_t)B_ * M1_ * KD;    // [64][4096][128]

  float* ws     = (float*)d_ws;
  float* P      = ws + WS_P;       // proj partials, later Py
  float* q      = ws + WS_Q;
  float* stats  = ws + WS_STATS;
  float* o      = ws + WS_O;
  float* o_part = ws + WS_OPART;

  k_proj_partial<<<dim3(16, 34), 256, 0, stream>>>(x, Wq, Wk, Wv, P);
  k_proj_reduce<<<1088, 256, 0, stream>>>(P, q, Kc, Vc);
  k_flash<<<dim3(32, 64), 256, 0, stream>>>(prevK, prevV, q, Kc, Vc, o_part, stats);
  k_combine<<<2048, 128, 0, stream>>>(o_part, stats, o);
  k_out_partial<<<dim3(32, 16), 256, 0, stream>>>(o, Wo, P);
  k_yreduce<<<1024, 256, 0, stream>>>(P, y);
}

// Round 6
// 275.353 us; speedup vs baseline: 8.3409x; 8.3409x over previous
//
#include <hip/hip_runtime.h>
#include <stdint.h>

#define B_  64
#define H_  32
#define D_  4096
#define KD  128
#define VD  128
#define M_  4095
#define M1_ 4096
#define NCHUNK 32
#define LOG2E 1.44269504088896f

// ---- workspace layout (float offsets) ----
#define WS_P      0ull
#define WS_Q      4456448ull
#define WS_STATS  4718592ull
#define WS_O      4849664ull
#define WS_OPART  5111808ull

#define WAITV(n) asm volatile("s_waitcnt vmcnt(" #n ")" ::: "memory")
#define WAITVL(n) asm volatile("s_waitcnt vmcnt(" #n ") lgkmcnt(0)" ::: "memory")
#define WAITL()  asm volatile("s_waitcnt lgkmcnt(0)" ::: "memory")
#define BAR()    __builtin_amdgcn_s_barrier()

typedef __attribute__((address_space(3))) char lds_char;
typedef const __attribute__((address_space(1))) char glb_char;

// ---------------- K1a: partial projections (q, k_new, v_new) ----------------
__global__ __launch_bounds__(256) void k_proj_partial(
    const float* __restrict__ x, const float* __restrict__ Wq,
    const float* __restrict__ Wk, const float* __restrict__ Wv,
    float* __restrict__ P) {
  __shared__ float xs[64][256];
  const int dc = blockIdx.x;
  const int hx = blockIdx.y;
  const int t  = threadIdx.x;
  const float* xsrc = x + dc * 256;
  #pragma unroll
  for (int j = 0; j < 16; ++j) {
    int f = t + 256 * j;
    int row = f >> 6, c4 = f & 63;
    *(float4*)&xs[row][c4 * 4] =
        *(const float4*)(xsrc + (size_t)row * D_ + c4 * 4);
  }
  __syncthreads();
  const int bq = t >> 4;
  const int kg = t & 15;
  const int b0 = bq * 4;
  const float* W = (hx < H_) ? (Wq + (size_t)hx * D_ * KD)
                             : ((hx == H_) ? Wk : Wv);
  const float* wp = W + (size_t)(dc * 256) * KD + kg * 8;
  float acc[4][8];
  #pragma unroll
  for (int i = 0; i < 4; ++i)
    #pragma unroll
    for (int j = 0; j < 8; ++j) acc[i][j] = 0.f;
  #pragma unroll 8
  for (int d = 0; d < 256; ++d) {
    float4 w0 = *(const float4*)(wp + (size_t)d * KD);
    float4 w1 = *(const float4*)(wp + (size_t)d * KD + 4);
    float xv[4];
    #pragma unroll
    for (int i = 0; i < 4; ++i) xv[i] = xs[b0 + i][d];
    #pragma unroll
    for (int i = 0; i < 4; ++i) {
      acc[i][0] += xv[i] * w0.x; acc[i][1] += xv[i] * w0.y;
      acc[i][2] += xv[i] * w0.z; acc[i][3] += xv[i] * w0.w;
      acc[i][4] += xv[i] * w1.x; acc[i][5] += xv[i] * w1.y;
      acc[i][6] += xv[i] * w1.z; acc[i][7] += xv[i] * w1.w;
    }
  }
  #pragma unroll
  for (int i = 0; i < 4; ++i) {
    size_t base = ((size_t)(dc * 64 + b0 + i) * 34 + hx) * KD + kg * 8;
    *(float4*)&P[base]     = make_float4(acc[i][0], acc[i][1], acc[i][2], acc[i][3]);
    *(float4*)&P[base + 4] = make_float4(acc[i][4], acc[i][5], acc[i][6], acc[i][7]);
  }
}

// ---------------- K1b: reduce partials -> q, Kc[.,M,:], Vc[.,M,:] ----------
__global__ __launch_bounds__(256) void k_proj_reduce(
    const float* __restrict__ P, float* __restrict__ q,
    float* __restrict__ Kc, float* __restrict__ Vc) {
  int i = blockIdx.x * 256 + threadIdx.x;
  int k = i & 127;
  int hx = (i >> 7) % 34;
  int b = i / (128 * 34);
  float s = 0.f;
  #pragma unroll
  for (int dc = 0; dc < 16; ++dc)
    s += P[(size_t)dc * (64 * 34 * 128) + (size_t)(b * 34 + hx) * 128 + k];
  if (hx < H_)       q[((size_t)b * H_ + hx) * KD + k] = s;
  else if (hx == H_) Kc[((size_t)b * M1_ + M_) * KD + k] = s;
  else               Vc[((size_t)b * M1_ + M_) * VD + k] = s;
}

// ---------------- K2: flash attention, async-pipelined ---------------------
// 8 tiles of 32 rows (4 K then 4 V) staged via global_load_lds into a
// 2-buffer ring. Counted vmcnt (never 0 mid-loop) keeps next tile's loads in
// flight across raw s_barriers. Global source is XOR-swizzled (col ^ row&7 in
// float4 units) so the linear LDS dest reads conflict-free; compute and the
// Kc/Vc copy-out apply the same involution.
__device__ __forceinline__ void stage_issue(
    const float* src, const float* app_row, float* lbuf, int m_lo, int t) {
  const int wb = t & ~63;   // wave-uniform thread base
  #pragma unroll
  for (int j = 0; j < 4; ++j) {
    int f = j * 256 + t;
    int r = f >> 5, p = f & 31;
    int m = m_lo + r;
    int g4 = p ^ (r & 7);
    const float* gp = (m < M_) ? (src + (size_t)m * 128 + g4 * 4)
                               : (app_row + g4 * 4);
    __builtin_amdgcn_global_load_lds(
        (glb_char*)gp, (lds_char*)(lbuf + (size_t)(j * 256 + wb) * 4),
        16, 0, 0);
  }
}

__device__ __forceinline__ void copy_out(
    const float* lbuf, float* dst, int m_lo, int t) {
  const int r = t >> 3;
  const int m = m_lo + r;
  float* drow = dst + (size_t)m * 128;
  #pragma unroll
  for (int jj = 0; jj < 4; ++jj) {
    int g4 = (t & 7) + jj * 8;
    int p = g4 ^ (r & 7);
    float4 v = *(const float4*)&lbuf[(r * 32 + p) * 4];
    *(float4*)(drow + g4 * 4) = v;   // unconditional: m==M_ rewrites identical bytes
  }
}

__global__ __launch_bounds__(256, 2) void k_flash(
    const float* __restrict__ prevK, const float* __restrict__ prevV,
    const float* __restrict__ q, float* __restrict__ Kc, float* __restrict__ Vc,
    float* __restrict__ o_part, float* __restrict__ stats) {
  __shared__ float buf[2][32 * 128];   // 32 KB ring
  __shared__ float qs[32][128];        // 16 KB (broadcast reads only)
  __shared__ float wl[128 * 36];       // 18 KB logits/weights [m][h]
  const int chunk = blockIdx.x;
  const int b = blockIdx.y;
  const int t = threadIdx.x;
  const int m0 = chunk * 128;

  const float* kbase = prevK + (size_t)b * M_ * KD;
  const float* vbase = prevV + (size_t)b * M_ * VD;
  const float* kapp  = Kc + ((size_t)b * M1_ + M_) * KD;
  const float* vapp  = Vc + ((size_t)b * M1_ + M_) * VD;
  float* kc = Kc + (size_t)b * M1_ * KD;
  float* vc = Vc + (size_t)b * M1_ * VD;

  // q -> regs -> LDS; stage0 issued in between so its latency overlaps
  const float* qsrc = q + (size_t)b * H_ * KD;
  float4 qv[4];
  #pragma unroll
  for (int j = 0; j < 4; ++j) {
    int f = j * 256 + t;
    qv[j] = *(const float4*)(qsrc + (size_t)(f >> 5) * KD + (f & 31) * 4);
  }
  stage_issue(kbase, kapp, buf[0], m0, t);          // stage K0
  #pragma unroll
  for (int j = 0; j < 4; ++j) {
    int f = j * 256 + t;
    *(float4*)&qs[f >> 5][(f & 31) * 4] = qv[j];
  }

  const int mg = t & 15, hg = t >> 4, h0 = hg * 2;      // logits mapping
  const int v4 = t & 31, hoct = t >> 5, h0v = hoct * 4; // PV mapping

  float4 a0 = {0,0,0,0}, a1 = {0,0,0,0}, a2 = {0,0,0,0}, a3 = {0,0,0,0};

  // ---------------- logits tile macro ----------------
#define LOGITS_TILE(S, BUFI)                                                  \
  {                                                                           \
    const float* lb = buf[BUFI];                                              \
    float c00 = 0.f, c01 = 0.f, c10 = 0.f, c11 = 0.f;                         \
    const int sw = (mg & 7);                                                  \
    _Pragma("unroll 4")                                                       \
    for (int k4 = 0; k4 < 32; ++k4) {                                         \
      int p = (k4 ^ sw) * 4;                                                  \
      float4 qa = *(const float4*)&qs[h0][k4 * 4];                            \
      float4 qb = *(const float4*)&qs[h0 + 1][k4 * 4];                        \
      float4 k0v = *(const float4*)&lb[mg * 128 + p];                         \
      float4 k1v = *(const float4*)&lb[(mg + 16) * 128 + p];                  \
      c00 += qa.x*k0v.x + qa.y*k0v.y + qa.z*k0v.z + qa.w*k0v.w;               \
      c01 += qa.x*k1v.x + qa.y*k1v.y + qa.z*k1v.z + qa.w*k1v.w;               \
      c10 += qb.x*k0v.x + qb.y*k0v.y + qb.z*k0v.z + qb.w*k0v.w;               \
      c11 += qb.x*k1v.x + qb.y*k1v.y + qb.z*k1v.z + qb.w*k1v.w;               \
    }                                                                         \
    wl[((S) * 32 + mg) * 36 + h0]          = c00;                             \
    wl[((S) * 32 + mg + 16) * 36 + h0]     = c01;                             \
    wl[((S) * 32 + mg) * 36 + h0 + 1]      = c10;                             \
    wl[((S) * 32 + mg + 16) * 36 + h0 + 1] = c11;                             \
  }

  // ---------------- PV tile macro ----------------
#define PV_TILE(S, BUFI)                                                      \
  {                                                                           \
    const float* lb = buf[BUFI];                                              \
    _Pragma("unroll 4")                                                       \
    for (int mm = 0; mm < 32; ++mm) {                                         \
      int p = (v4 ^ (mm & 7)) * 4;                                            \
      float4 gv = *(const float4*)&lb[mm * 128 + p];                          \
      float4 w4 = *(const float4*)&wl[((S) * 32 + mm) * 36 + h0v];            \
      a0.x += w4.x*gv.x; a0.y += w4.x*gv.y; a0.z += w4.x*gv.z; a0.w += w4.x*gv.w; \
      a1.x += w4.y*gv.x; a1.y += w4.y*gv.y; a1.z += w4.y*gv.z; a1.w += w4.y*gv.w; \
      a2.x += w4.z*gv.x; a2.y += w4.z*gv.y; a2.z += w4.z*gv.z; a2.w += w4.z*gv.w; \
      a3.x += w4.w*gv.x; a3.y += w4.w*gv.y; a3.z += w4.w*gv.z; a3.w += w4.w*gv.w; \
    }                                                                         \
  }

  // tile 0 (K0 in buf0)
  stage_issue(kbase, kapp, buf[1], m0 + 32, t);     // K1
  WAITVL(4); BAR();
  LOGITS_TILE(0, 0);
  copy_out(buf[0], kc, m0, t);
  WAITL(); BAR();
  // tile 1 (K1 in buf1)
  stage_issue(kbase, kapp, buf[0], m0 + 64, t);     // K2
  WAITVL(8); BAR();
  LOGITS_TILE(1, 1);
  copy_out(buf[1], kc, m0 + 32, t);
  WAITL(); BAR();
  // tile 2 (K2 in buf0)
  stage_issue(kbase, kapp, buf[1], m0 + 96, t);     // K3
  WAITVL(8); BAR();
  LOGITS_TILE(2, 0);
  copy_out(buf[0], kc, m0 + 64, t);
  WAITL(); BAR();
  // tile 3 (K3 in buf1)
  stage_issue(vbase, vapp, buf[0], m0, t);          // V0
  WAITVL(8); BAR();
  LOGITS_TILE(3, 1);
  copy_out(buf[1], kc, m0 + 96, t);
  WAITL(); BAR();

  // softmax over wl columns (V0 loads in flight)
  {
    const int h = t >> 3, s8 = t & 7;
    float vals[16];
    float mx = -3.402823466e38f;
    #pragma unroll
    for (int i = 0; i < 16; ++i) {
      vals[i] = wl[(i * 8 + s8) * 36 + h];
      mx = fmaxf(mx, vals[i]);
    }
    mx = fmaxf(mx, __shfl_xor(mx, 1));
    mx = fmaxf(mx, __shfl_xor(mx, 2));
    mx = fmaxf(mx, __shfl_xor(mx, 4));
    float sum = 0.f;
    #pragma unroll
    for (int i = 0; i < 16; ++i) {
      float e = exp2f((vals[i] - mx) * LOG2E);
      wl[(i * 8 + s8) * 36 + h] = e;
      sum += e;
    }
    sum += __shfl_xor(sum, 1);
    sum += __shfl_xor(sum, 2);
    sum += __shfl_xor(sum, 4);
    if (s8 == 0) {
      size_t sb = (((size_t)b * H_ + h) * NCHUNK + chunk) * 2;
      stats[sb]     = mx;
      stats[sb + 1] = sum;
    }
  }
  WAITL(); BAR();

  // tile 4 (V0 in buf0)
  stage_issue(vbase, vapp, buf[1], m0 + 32, t);     // V1
  WAITVL(9); BAR();
  PV_TILE(0, 0);
  copy_out(buf[0], vc, m0, t);
  WAITL(); BAR();
  // tile 5 (V1 in buf1)
  stage_issue(vbase, vapp, buf[0], m0 + 64, t);     // V2
  WAITVL(8); BAR();
  PV_TILE(1, 1);
  copy_out(buf[1], vc, m0 + 32, t);
  WAITL(); BAR();
  // tile 6 (V2 in buf0)
  stage_issue(vbase, vapp, buf[1], m0 + 96, t);     // V3
  WAITVL(8); BAR();
  PV_TILE(2, 0);
  copy_out(buf[0], vc, m0 + 64, t);
  WAITL(); BAR();
  // tile 7 (V3 in buf1)
  WAITVL(4); BAR();
  PV_TILE(3, 1);
  copy_out(buf[1], vc, m0 + 96, t);

  size_t base = ((size_t)(chunk * B_ + b) * H_ + h0v) * VD + v4 * 4;
  *(float4*)&o_part[base]          = a0;
  *(float4*)&o_part[base + VD]     = a1;
  *(float4*)&o_part[base + 2 * VD] = a2;
  *(float4*)&o_part[base + 3 * VD] = a3;
#undef LOGITS_TILE
#undef PV_TILE
}

// ---------------- K3: flash combine -> o -----------------------------------
__global__ __launch_bounds__(128) void k_combine(
    const float* __restrict__ o_part, const float* __restrict__ stats,
    float* __restrict__ o) {
  const int bh = blockIdx.x;
  const int t = threadIdx.x;
  __shared__ float st[64];
  if (t < 64) st[t] = stats[(size_t)bh * 64 + t];
  __syncthreads();
  float M = -3.402823466e38f;
  #pragma unroll
  for (int c = 0; c < NCHUNK; ++c) M = fmaxf(M, st[2 * c]);
  float wc[NCHUNK];
  float denom = 0.f;
  #pragma unroll
  for (int c = 0; c < NCHUNK; ++c) {
    float e = exp2f((st[2 * c] - M) * LOG2E);
    wc[c] = e;
    denom += st[2 * c + 1] * e;
  }
  const float inv = 1.0f / denom;
  const int b = bh >> 5, h = bh & 31;
  float acc = 0.f;
  #pragma unroll 4
  for (int c = 0; c < NCHUNK; ++c)
    acc += wc[c] * o_part[((size_t)(c * B_ + b) * H_ + h) * VD + t];
  o[(size_t)bh * VD + t] = acc * inv;
}

// ---------------- K5: partial y = o . Wo -----------------------------------
__global__ __launch_bounds__(256) void k_out_partial(
    const float* __restrict__ o, const float* __restrict__ Wo,
    float* __restrict__ Py) {
  __shared__ float os[64][256];
  const int dc = blockIdx.x;
  const int hvc = blockIdx.y;
  const int t = threadIdx.x;
  #pragma unroll
  for (int j = 0; j < 16; ++j) {
    int f = t + 256 * j;
    int row = f >> 6, c4 = f & 63;
    *(float4*)&os[row][c4 * 4] =
        *(const float4*)(o + (size_t)row * 4096 + hvc * 256 + c4 * 4);
  }
  __syncthreads();
  const int bq = t >> 4, dg = t & 15;
  const int b0 = bq * 4;
  const float* wp = Wo + (size_t)(hvc * 256) * D_ + dc * 128 + dg * 8;
  float acc[4][8];
  #pragma unroll
  for (int i = 0; i < 4; ++i)
    #pragma unroll
    for (int j = 0; j < 8; ++j) acc[i][j] = 0.f;
  #pragma unroll 8
  for (int hv = 0; hv < 256; ++hv) {
    float4 w0 = *(const float4*)(wp + (size_t)hv * D_);
    float4 w1 = *(const float4*)(wp + (size_t)hv * D_ + 4);
    float ov[4];
    #pragma unroll
    for (int i = 0; i < 4; ++i) ov[i] = os[b0 + i][hv];
    #pragma unroll
    for (int i = 0; i < 4; ++i) {
      acc[i][0] += ov[i] * w0.x; acc[i][1] += ov[i] * w0.y;
      acc[i][2] += ov[i] * w0.z; acc[i][3] += ov[i] * w0.w;
      acc[i][4] += ov[i] * w1.x; acc[i][5] += ov[i] * w1.y;
      acc[i][6] += ov[i] * w1.z; acc[i][7] += ov[i] * w1.w;
    }
  }
  #pragma unroll
  for (int i = 0; i < 4; ++i) {
    size_t base = ((size_t)hvc * 64 + b0 + i) * 4096 + dc * 128 + dg * 8;
    *(float4*)&Py[base]     = make_float4(acc[i][0], acc[i][1], acc[i][2], acc[i][3]);
    *(float4*)&Py[base + 4] = make_float4(acc[i][4], acc[i][5], acc[i][6], acc[i][7]);
  }
}

// ---------------- K5b: reduce partial y ------------------------------------
__global__ __launch_bounds__(256) void k_yreduce(
    const float* __restrict__ Py, float* __restrict__ y) {
  int i = blockIdx.x * 256 + threadIdx.x;
  float s = 0.f;
  #pragma unroll
  for (int c = 0; c < 16; ++c) s += Py[(size_t)c * 262144 + i];
  y[i] = s;
}

extern "C" void kernel_launch(void* const* d_in, const int* in_sizes, int n_in,
                              void* d_out, int out_size, void* d_ws, size_t ws_size,
                              hipStream_t stream) {
  const float* x     = (const float*)d_in[0];
  const float* prevK = (const float*)d_in[1];
  const float* prevV = (const float*)d_in[2];
  const float* Wq    = (const float*)d_in[3];
  const float* Wk    = (const float*)d_in[4];
  const float* Wv    = (const float*)d_in[5];
  const float* Wo    = (const float*)d_in[6];

  float* y  = (float*)d_out;
  float* Kc = y + (size_t)B_ * D_;
  float* Vc = Kc + (size_t)B_ * M1_ * KD;

  float* ws     = (float*)d_ws;
  float* P      = ws + WS_P;
  float* q      = ws + WS_Q;
  float* stats  = ws + WS_STATS;
  float* o      = ws + WS_O;
  float* o_part = ws + WS_OPART;

  k_proj_partial<<<dim3(16, 34), 256, 0, stream>>>(x, Wq, Wk, Wv, P);
  k_proj_reduce<<<1088, 256, 0, stream>>>(P, q, Kc, Vc);
  k_flash<<<dim3(32, 64), 256, 0, stream>>>(prevK, prevV, q, Kc, Vc, o_part, stats);
  k_combine<<<2048, 128, 0, stream>>>(o_part, stats, o);
  k_out_partial<<<dim3(32, 16), 256, 0, stream>>>(o, Wo, P);
  k_yreduce<<<1024, 256, 0, stream>>>(P, y);
}

// Round 7
// 262.043 us; speedup vs baseline: 8.7646x; 1.0508x over previous
//
#include <hip/hip_runtime.h>
#include <stdint.h>

#define B_  64
#define H_  32
#define D_  4096
#define KD  128
#define VD  128
#define M_  4095
#define M1_ 4096
#define NCHUNK 32
#define LOG2E 1.44269504088896f

// ---- workspace layout (float offsets) ----
#define WS_P      0ull
#define WS_Q      4456448ull
#define WS_STATS  4718592ull
#define WS_O      4849664ull
#define WS_OPART  5111808ull

#define WAITVL(n) asm volatile("s_waitcnt vmcnt(" #n ") lgkmcnt(0)" ::: "memory")
#define WAITL()  asm volatile("s_waitcnt lgkmcnt(0)" ::: "memory")
#define BAR()    __builtin_amdgcn_s_barrier()

typedef __attribute__((address_space(3))) char lds_char;
typedef const __attribute__((address_space(1))) char glb_char;

// ---------------- K1a: partial projections (q, k_new, v_new) ----------------
__global__ __launch_bounds__(256) void k_proj_partial(
    const float* __restrict__ x, const float* __restrict__ Wq,
    const float* __restrict__ Wk, const float* __restrict__ Wv,
    float* __restrict__ P) {
  __shared__ float xs[64][260];   // padded: 2-way max on column reads
  const int dc = blockIdx.x;
  const int hx = blockIdx.y;
  const int t  = threadIdx.x;
  const float* xsrc = x + dc * 256;
  #pragma unroll
  for (int j = 0; j < 16; ++j) {
    int f = t + 256 * j;
    int row = f >> 6, c4 = f & 63;
    *(float4*)&xs[row][c4 * 4] =
        *(const float4*)(xsrc + (size_t)row * D_ + c4 * 4);
  }
  __syncthreads();
  const int bq = t >> 4;
  const int kg = t & 15;
  const int b0 = bq * 4;
  const float* W = (hx < H_) ? (Wq + (size_t)hx * D_ * KD)
                             : ((hx == H_) ? Wk : Wv);
  const float* wp = W + (size_t)(dc * 256) * KD + kg * 8;
  float acc[4][8];
  #pragma unroll
  for (int i = 0; i < 4; ++i)
    #pragma unroll
    for (int j = 0; j < 8; ++j) acc[i][j] = 0.f;
  #pragma unroll 8
  for (int d = 0; d < 256; ++d) {
    float4 w0 = *(const float4*)(wp + (size_t)d * KD);
    float4 w1 = *(const float4*)(wp + (size_t)d * KD + 4);
    float xv[4];
    #pragma unroll
    for (int i = 0; i < 4; ++i) xv[i] = xs[b0 + i][d];
    #pragma unroll
    for (int i = 0; i < 4; ++i) {
      acc[i][0] += xv[i] * w0.x; acc[i][1] += xv[i] * w0.y;
      acc[i][2] += xv[i] * w0.z; acc[i][3] += xv[i] * w0.w;
      acc[i][4] += xv[i] * w1.x; acc[i][5] += xv[i] * w1.y;
      acc[i][6] += xv[i] * w1.z; acc[i][7] += xv[i] * w1.w;
    }
  }
  #pragma unroll
  for (int i = 0; i < 4; ++i) {
    size_t base = ((size_t)(dc * 64 + b0 + i) * 34 + hx) * KD + kg * 8;
    *(float4*)&P[base]     = make_float4(acc[i][0], acc[i][1], acc[i][2], acc[i][3]);
    *(float4*)&P[base + 4] = make_float4(acc[i][4], acc[i][5], acc[i][6], acc[i][7]);
  }
}

// ---------------- K1b: reduce partials -> q, Kc[.,M,:], Vc[.,M,:] ----------
__global__ __launch_bounds__(256) void k_proj_reduce(
    const float* __restrict__ P, float* __restrict__ q,
    float* __restrict__ Kc, float* __restrict__ Vc) {
  int i = blockIdx.x * 256 + threadIdx.x;
  int k = i & 127;
  int hx = (i >> 7) % 34;
  int b = i / (128 * 34);
  float s = 0.f;
  #pragma unroll
  for (int dc = 0; dc < 16; ++dc)
    s += P[(size_t)dc * (64 * 34 * 128) + (size_t)(b * 34 + hx) * 128 + k];
  if (hx < H_)       q[((size_t)b * H_ + hx) * KD + k] = s;
  else if (hx == H_) Kc[((size_t)b * M1_ + M_) * KD + k] = s;
  else               Vc[((size_t)b * M1_ + M_) * VD + k] = s;
}

// ---------------- K2: flash attention, async-pipelined ---------------------
// 8 tiles of 32 rows (4 K, 4 V) via global_load_lds 2-buffer ring, counted
// vmcnt. Logits accumulate in REGISTERS across all K tiles; softmax is
// in-register (shfl over the 16-lane mg-group); weights written once to the
// qs/wl LDS union. LDS = 32K (buf) + 18K (union) = 50 KB -> 3 blocks/CU.
__device__ __forceinline__ void stage_issue(
    const float* src, const float* app_row, float* lbuf, int m_lo, int t) {
  const int wb = t & ~63;   // wave-uniform thread base
  #pragma unroll
  for (int j = 0; j < 4; ++j) {
    int f = j * 256 + t;
    int r = f >> 5, p = f & 31;
    int m = m_lo + r;
    int g4 = p ^ (r & 7);
    const float* gp = (m < M_) ? (src + (size_t)m * 128 + g4 * 4)
                               : (app_row + g4 * 4);
    __builtin_amdgcn_global_load_lds(
        (glb_char*)gp, (lds_char*)(lbuf + (size_t)(j * 256 + wb) * 4),
        16, 0, 0);
  }
}

__device__ __forceinline__ void copy_out(
    const float* lbuf, float* dst, int m_lo, int t) {
  const int r = t >> 3;
  const int m = m_lo + r;
  float* drow = dst + (size_t)m * 128;
  #pragma unroll
  for (int jj = 0; jj < 4; ++jj) {
    int g4 = (t & 7) + jj * 8;
    int p = g4 ^ (r & 7);
    float4 v = *(const float4*)&lbuf[(r * 32 + p) * 4];
    *(float4*)(drow + g4 * 4) = v;   // m==M_ rewrites identical bytes
  }
}

__global__ __launch_bounds__(256, 3) void k_flash(
    const float* __restrict__ prevK, const float* __restrict__ prevV,
    const float* __restrict__ q, float* __restrict__ Kc, float* __restrict__ Vc,
    float* __restrict__ o_part, float* __restrict__ stats) {
  __shared__ float buf[2][32 * 128];   // 32 KB ring
  __shared__ float upool[4608];        // K phase: qs[32][132]; V phase: wl[128][36]
  const int chunk = blockIdx.x;
  const int b = blockIdx.y;
  const int t = threadIdx.x;
  const int m0 = chunk * 128;

  const float* kbase = prevK + (size_t)b * M_ * KD;
  const float* vbase = prevV + (size_t)b * M_ * VD;
  const float* kapp  = Kc + ((size_t)b * M1_ + M_) * KD;
  const float* vapp  = Vc + ((size_t)b * M1_ + M_) * VD;
  float* kc = Kc + (size_t)b * M1_ * KD;
  float* vc = Vc + (size_t)b * M1_ * VD;

  // q -> regs -> LDS (stride 132); K0 staged in between
  const float* qsrc = q + (size_t)b * H_ * KD;
  float4 qv4[4];
  #pragma unroll
  for (int j = 0; j < 4; ++j) {
    int f = j * 256 + t;
    qv4[j] = *(const float4*)(qsrc + (size_t)(f >> 5) * KD + (f & 31) * 4);
  }
  stage_issue(kbase, kapp, buf[0], m0, t);          // K0
  #pragma unroll
  for (int j = 0; j < 4; ++j) {
    int f = j * 256 + t;
    *(float4*)&upool[(f >> 5) * 132 + (f & 31) * 4] = qv4[j];
  }

  const int mg = t & 15, hg = t >> 4, h0 = hg * 2;      // logits mapping
  const int v4 = t & 31, hoct = t >> 5, h0v = hoct * 4; // PV mapping

  float accL0[8], accL1[8];   // logits regs: [tile*2 + i], m = tile*32+mg+16i

#define LOGITS_TILE(S, BUFI)                                                  \
  {                                                                           \
    const float* lb = buf[BUFI];                                              \
    float c00 = 0.f, c01 = 0.f, c10 = 0.f, c11 = 0.f;                         \
    const int sw = (mg & 7);                                                  \
    _Pragma("unroll 4")                                                       \
    for (int k4 = 0; k4 < 32; ++k4) {                                         \
      int p = (k4 ^ sw) * 4;                                                  \
      float4 qa = *(const float4*)&upool[h0 * 132 + k4 * 4];                  \
      float4 qb = *(const float4*)&upool[(h0 + 1) * 132 + k4 * 4];            \
      float4 k0v = *(const float4*)&lb[mg * 128 + p];                         \
      float4 k1v = *(const float4*)&lb[(mg + 16) * 128 + p];                  \
      c00 += qa.x*k0v.x + qa.y*k0v.y + qa.z*k0v.z + qa.w*k0v.w;               \
      c01 += qa.x*k1v.x + qa.y*k1v.y + qa.z*k1v.z + qa.w*k1v.w;               \
      c10 += qb.x*k0v.x + qb.y*k0v.y + qb.z*k0v.z + qb.w*k0v.w;               \
      c11 += qb.x*k1v.x + qb.y*k1v.y + qb.z*k1v.z + qb.w*k1v.w;               \
    }                                                                         \
    accL0[(S) * 2]     = c00;                                                 \
    accL0[(S) * 2 + 1] = c01;                                                 \
    accL1[(S) * 2]     = c10;                                                 \
    accL1[(S) * 2 + 1] = c11;                                                 \
  }

#define PV_TILE(S, BUFI)                                                      \
  {                                                                           \
    const float* lb = buf[BUFI];                                              \
    _Pragma("unroll 4")                                                       \
    for (int mm = 0; mm < 32; ++mm) {                                         \
      int p = (v4 ^ (mm & 7)) * 4;                                            \
      float4 gv = *(const float4*)&lb[mm * 128 + p];                          \
      float4 w4 = *(const float4*)&upool[((S) * 32 + mm) * 36 + h0v];         \
      a0.x += w4.x*gv.x; a0.y += w4.x*gv.y; a0.z += w4.x*gv.z; a0.w += w4.x*gv.w; \
      a1.x += w4.y*gv.x; a1.y += w4.y*gv.y; a1.z += w4.y*gv.z; a1.w += w4.y*gv.w; \
      a2.x += w4.z*gv.x; a2.y += w4.z*gv.y; a2.z += w4.z*gv.z; a2.w += w4.z*gv.w; \
      a3.x += w4.w*gv.x; a3.y += w4.w*gv.y; a3.z += w4.w*gv.z; a3.w += w4.w*gv.w; \
    }                                                                         \
  }

  // ---- K phase ----
  stage_issue(kbase, kapp, buf[1], m0 + 32, t);     // K1
  WAITVL(4); BAR();
  LOGITS_TILE(0, 0);
  copy_out(buf[0], kc, m0, t);
  WAITL(); BAR();

  stage_issue(kbase, kapp, buf[0], m0 + 64, t);     // K2
  WAITVL(8); BAR();
  LOGITS_TILE(1, 1);
  copy_out(buf[1], kc, m0 + 32, t);
  WAITL(); BAR();

  stage_issue(kbase, kapp, buf[1], m0 + 96, t);     // K3
  WAITVL(8); BAR();
  LOGITS_TILE(2, 0);
  copy_out(buf[0], kc, m0 + 64, t);
  WAITL(); BAR();

  stage_issue(vbase, vapp, buf[0], m0, t);          // V0
  WAITVL(8); BAR();
  LOGITS_TILE(3, 1);
  copy_out(buf[1], kc, m0 + 96, t);
  WAITL(); BAR();   // all qs reads done -> upool becomes wl

  // ---- in-register softmax over the 16-lane mg-group ----
  {
    float mx0 = -3.402823466e38f, mx1 = -3.402823466e38f;
    #pragma unroll
    for (int j = 0; j < 8; ++j) {
      mx0 = fmaxf(mx0, accL0[j]);
      mx1 = fmaxf(mx1, accL1[j]);
    }
    #pragma unroll
    for (int off = 1; off <= 8; off <<= 1) {
      mx0 = fmaxf(mx0, __shfl_xor(mx0, off));
      mx1 = fmaxf(mx1, __shfl_xor(mx1, off));
    }
    float s0 = 0.f, s1 = 0.f;
    #pragma unroll
    for (int j = 0; j < 8; ++j) {
      float e0 = exp2f((accL0[j] - mx0) * LOG2E); accL0[j] = e0; s0 += e0;
      float e1 = exp2f((accL1[j] - mx1) * LOG2E); accL1[j] = e1; s1 += e1;
    }
    #pragma unroll
    for (int off = 1; off <= 8; off <<= 1) {
      s0 += __shfl_xor(s0, off);
      s1 += __shfl_xor(s1, off);
    }
    #pragma unroll
    for (int s = 0; s < 4; ++s)
      #pragma unroll
      for (int i = 0; i < 2; ++i) {
        int m = s * 32 + mg + 16 * i;
        upool[m * 36 + h0]     = accL0[s * 2 + i];
        upool[m * 36 + h0 + 1] = accL1[s * 2 + i];
      }
    if (mg == 0) {   // 2 stores per wave -> vmcnt +2
      size_t sb0 = (((size_t)b * H_ + h0) * NCHUNK + chunk) * 2;
      *(float2*)&stats[sb0] = make_float2(mx0, s0);
      size_t sb1 = (((size_t)b * H_ + h0 + 1) * NCHUNK + chunk) * 2;
      *(float2*)&stats[sb1] = make_float2(mx1, s1);
    }
  }
  WAITL(); BAR();   // wl visible

  // ---- V phase ----
  float4 a0 = {0,0,0,0}, a1 = {0,0,0,0}, a2 = {0,0,0,0}, a3 = {0,0,0,0};

  stage_issue(vbase, vapp, buf[1], m0 + 32, t);     // V1
  WAITVL(10); BAR();                                // K3st(4)+stats(2)+V1(4) newer than V0
  PV_TILE(0, 0);
  copy_out(buf[0], vc, m0, t);
  WAITL(); BAR();

  stage_issue(vbase, vapp, buf[0], m0 + 64, t);     // V2
  WAITVL(8); BAR();
  PV_TILE(1, 1);
  copy_out(buf[1], vc, m0 + 32, t);
  WAITL(); BAR();

  stage_issue(vbase, vapp, buf[1], m0 + 96, t);     // V3
  WAITVL(8); BAR();
  PV_TILE(2, 0);
  copy_out(buf[0], vc, m0 + 64, t);
  WAITL(); BAR();

  WAITVL(4); BAR();
  PV_TILE(3, 1);
  copy_out(buf[1], vc, m0 + 96, t);

  size_t base = ((size_t)(chunk * B_ + b) * H_ + h0v) * VD + v4 * 4;
  *(float4*)&o_part[base]          = a0;
  *(float4*)&o_part[base + VD]     = a1;
  *(float4*)&o_part[base + 2 * VD] = a2;
  *(float4*)&o_part[base + 3 * VD] = a3;
#undef LOGITS_TILE
#undef PV_TILE
}

// ---------------- K3: flash combine -> o -----------------------------------
__global__ __launch_bounds__(128) void k_combine(
    const float* __restrict__ o_part, const float* __restrict__ stats,
    float* __restrict__ o) {
  const int bh = blockIdx.x;
  const int t = threadIdx.x;
  __shared__ float st[64];
  if (t < 64) st[t] = stats[(size_t)bh * 64 + t];
  __syncthreads();
  float M = -3.402823466e38f;
  #pragma unroll
  for (int c = 0; c < NCHUNK; ++c) M = fmaxf(M, st[2 * c]);
  float wc[NCHUNK];
  float denom = 0.f;
  #pragma unroll
  for (int c = 0; c < NCHUNK; ++c) {
    float e = exp2f((st[2 * c] - M) * LOG2E);
    wc[c] = e;
    denom += st[2 * c + 1] * e;
  }
  const float inv = 1.0f / denom;
  const int b = bh >> 5, h = bh & 31;
  float acc = 0.f;
  #pragma unroll 4
  for (int c = 0; c < NCHUNK; ++c)
    acc += wc[c] * o_part[((size_t)(c * B_ + b) * H_ + h) * VD + t];
  o[(size_t)bh * VD + t] = acc * inv;
}

// ---------------- K5: partial y = o . Wo -----------------------------------
__global__ __launch_bounds__(256) void k_out_partial(
    const float* __restrict__ o, const float* __restrict__ Wo,
    float* __restrict__ Py) {
  __shared__ float os[64][260];   // padded
  const int dc = blockIdx.x;
  const int hvc = blockIdx.y;
  const int t = threadIdx.x;
  #pragma unroll
  for (int j = 0; j < 16; ++j) {
    int f = t + 256 * j;
    int row = f >> 6, c4 = f & 63;
    *(float4*)&os[row][c4 * 4] =
        *(const float4*)(o + (size_t)row * 4096 + hvc * 256 + c4 * 4);
  }
  __syncthreads();
  const int bq = t >> 4, dg = t & 15;
  const int b0 = bq * 4;
  const float* wp = Wo + (size_t)(hvc * 256) * D_ + dc * 128 + dg * 8;
  float acc[4][8];
  #pragma unroll
  for (int i = 0; i < 4; ++i)
    #pragma unroll
    for (int j = 0; j < 8; ++j) acc[i][j] = 0.f;
  #pragma unroll 8
  for (int hv = 0; hv < 256; ++hv) {
    float4 w0 = *(const float4*)(wp + (size_t)hv * D_);
    float4 w1 = *(const float4*)(wp + (size_t)hv * D_ + 4);
    float ov[4];
    #pragma unroll
    for (int i = 0; i < 4; ++i) ov[i] = os[b0 + i][hv];
    #pragma unroll
    for (int i = 0; i < 4; ++i) {
      acc[i][0] += ov[i] * w0.x; acc[i][1] += ov[i] * w0.y;
      acc[i][2] += ov[i] * w0.z; acc[i][3] += ov[i] * w0.w;
      acc[i][4] += ov[i] * w1.x; acc[i][5] += ov[i] * w1.y;
      acc[i][6] += ov[i] * w1.z; acc[i][7] += ov[i] * w1.w;
    }
  }
  #pragma unroll
  for (int i = 0; i < 4; ++i) {
    size_t base = ((size_t)hvc * 64 + b0 + i) * 4096 + dc * 128 + dg * 8;
    *(float4*)&Py[base]     = make_float4(acc[i][0], acc[i][1], acc[i][2], acc[i][3]);
    *(float4*)&Py[base + 4] = make_float4(acc[i][4], acc[i][5], acc[i][6], acc[i][7]);
  }
}

// ---------------- K5b: reduce partial y ------------------------------------
__global__ __launch_bounds__(256) void k_yreduce(
    const float* __restrict__ Py, float* __restrict__ y) {
  int i = blockIdx.x * 256 + threadIdx.x;
  float s = 0.f;
  #pragma unroll
  for (int c = 0; c < 16; ++c) s += Py[(size_t)c * 262144 + i];
  y[i] = s;
}

extern "C" void kernel_launch(void* const* d_in, const int* in_sizes, int n_in,
                              void* d_out, int out_size, void* d_ws, size_t ws_size,
                              hipStream_t stream) {
  const float* x     = (const float*)d_in[0];
  const float* prevK = (const float*)d_in[1];
  const float* prevV = (const float*)d_in[2];
  const float* Wq    = (const float*)d_in[3];
  const float* Wk    = (const float*)d_in[4];
  const float* Wv    = (const float*)d_in[5];
  const float* Wo    = (const float*)d_in[6];

  float* y  = (float*)d_out;
  float* Kc = y + (size_t)B_ * D_;
  float* Vc = Kc + (size_t)B_ * M1_ * KD;

  float* ws     = (float*)d_ws;
  float* P      = ws + WS_P;
  float* q      = ws + WS_Q;
  float* stats  = ws + WS_STATS;
  float* o      = ws + WS_O;
  float* o_part = ws + WS_OPART;

  k_proj_partial<<<dim3(16, 34), 256, 0, stream>>>(x, Wq, Wk, Wv, P);
  k_proj_reduce<<<1088, 256, 0, stream>>>(P, q, Kc, Vc);
  k_flash<<<dim3(32, 64), 256, 0, stream>>>(prevK, prevV, q, Kc, Vc, o_part, stats);
  k_combine<<<2048, 128, 0, stream>>>(o_part, stats, o);
  k_out_partial<<<dim3(32, 16), 256, 0, stream>>>(o, Wo, P);
  k_yreduce<<<1024, 256, 0, stream>>>(P, y);
}